// Round 14
// baseline (82.104 us; speedup 1.0000x reference)
//
#include <hip/hip_runtime.h>
#include <math.h>

#define BB 4
#define TT 1024
#define EE 512
#define HH 8
#define DD 64
#define BT (BB * TT)   // 4096

typedef _Float16 f16;
typedef __attribute__((ext_vector_type(8))) _Float16 f16x8;
typedef __attribute__((ext_vector_type(4))) float f32x4;
typedef __attribute__((ext_vector_type(16))) float f32x16;

// direct global->LDS DMA, 16B per lane. LDS dest = wave-uniform base + lane*16.
__device__ __forceinline__ void dma16(const f16* g, char* l) {
    __builtin_amdgcn_global_load_lds(
        (const __attribute__((address_space(1))) void*)g,
        (__attribute__((address_space(3))) void*)l, 16, 0, 0);
}

// ---------------------------------------------------------------------------
// Prep: y=0..3 weight planes (transposed f16), y=4/5 split q/kv into hi+lo
// f16 planes [BT][512]. Grid (1024, 6).
// ---------------------------------------------------------------------------
__global__ __launch_bounds__(256) void prep_k(
    const float* __restrict__ q, const float* __restrict__ kv,
    const float* __restrict__ Wq, const float* __restrict__ Wk,
    const float* __restrict__ Wv, const float* __restrict__ Wo,
    f16* __restrict__ wqh, f16* __restrict__ wql,
    f16* __restrict__ wkh, f16* __restrict__ wkl,
    f16* __restrict__ wvh, f16* __restrict__ woh,
    f16* __restrict__ qAhi, f16* __restrict__ qAlo,
    f16* __restrict__ kvAhi, f16* __restrict__ kvAlo) {
    const int t = threadIdx.x;
    const int y = blockIdx.y;
    if (y < 4) {
        int idx = blockIdx.x * 256 + t;        // 512*512 elems
        int k = idx & (EE - 1);
        int n = idx >> 9;
        if (y == 0) {
            float v = Wq[k * EE + n] * 512.0f; // fold dk*D scale (exact pow2)
            f16 hi = (f16)v;
            wqh[n * EE + k] = hi;
            wql[n * EE + k] = (f16)(v - (float)hi);
        } else if (y == 1) {
            int d = n >> 3, h = n & 7;
            int sn = (((DD - d) & (DD - 1)) << 3) | h;  // K'[.,d]=K[.,(D-d)%D]
            float v = Wk[k * EE + sn];
            f16 hi = (f16)v;
            wkh[n * EE + k] = hi;
            wkl[n * EE + k] = (f16)(v - (float)hi);
        } else if (y == 2) {
            wvh[n * EE + k] = (f16)Wv[k * EE + n];
        } else {
            woh[n * EE + k] = (f16)Wo[k * EE + n];
        }
    } else {
        const float* src = (y == 4) ? q : kv;
        f16* dh = (y == 4) ? qAhi : kvAhi;
        f16* dl = (y == 4) ? qAlo : kvAlo;
        int base = (blockIdx.x * 256 + t) * 8;
        float4 a = *(const float4*)&src[base];
        float4 c = *(const float4*)&src[base + 4];
        float xs[8] = {a.x, a.y, a.z, a.w, c.x, c.y, c.z, c.w};
        f16x8 hi, lo;
#pragma unroll
        for (int e = 0; e < 8; ++e) {
            f16 hh = (f16)xs[e];
            hi[e] = hh;
            lo[e] = (f16)(xs[e] - (float)hh);
        }
        *(f16x8*)&dh[base] = hi;
        *(f16x8*)&dl[base] = lo;
    }
}

// ---------------------------------------------------------------------------
// Fused projection with global_load_lds staging (unchanged from R13).
// ---------------------------------------------------------------------------
__global__ __launch_bounds__(256) void proj_k(
    const f16* __restrict__ qAhi, const f16* __restrict__ qAlo,
    const f16* __restrict__ kvAhi, const f16* __restrict__ kvAlo,
    const f16* __restrict__ wqh, const f16* __restrict__ wql,
    const f16* __restrict__ wkh, const f16* __restrict__ wkl,
    const f16* __restrict__ wvh,
    f16* __restrict__ qhi, f16* __restrict__ qlo,
    f16* __restrict__ kthi, f16* __restrict__ ktlo, f16* __restrict__ vP) {
    __shared__ __align__(16) f16 A_s[2][2][128][32];   // 32 KB
    __shared__ __align__(16) f16 W_s[2][3][64][32];    // 24 KB
    f16 (*Ep)[136] = reinterpret_cast<f16(*)[136]>(&A_s[0][0][0][0]);

    const int t = threadIdx.x;
    const int w = t >> 6, l = t & 63;
    const int wm = w >> 1, wn = w & 1;
    const int fr = l & 15, fc = l >> 4;
    const int m0b = blockIdx.x * 128;
    const int n0b = blockIdx.y * 64;
    const int z   = blockIdx.z;

    const f16* AH = z ? kvAhi : qAhi;
    const f16* AL = z ? kvAlo : qAlo;
    const f16* WH = z ? wkh : wqh;
    const f16* WL = z ? wkl : wql;

    f32x4 accK[4][2], accV[4][2];
#pragma unroll
    for (int i = 0; i < 4; ++i)
#pragma unroll
        for (int j = 0; j < 2; ++j) {
            accK[i][j] = f32x4{0.f, 0.f, 0.f, 0.f};
            accV[i][j] = f32x4{0.f, 0.f, 0.f, 0.f};
        }

    auto stageDMA = [&](int bf, int k0) {
#pragma unroll
        for (int i = 0; i < 2; ++i) {
            int slot = (i * 4 + w) * 64 + l;
            int r = slot >> 2, qv = slot & 3;
            const f16* gh = AH + (size_t)(m0b + r) * EE + k0 + qv * 8;
            const f16* gl = AL + (size_t)(m0b + r) * EE + k0 + qv * 8;
            dma16(gh, (char*)&A_s[bf][0][0][0] + (i * 4 + w) * 1024);
            dma16(gl, (char*)&A_s[bf][1][0][0] + (i * 4 + w) * 1024);
        }
        {
            int slot = w * 64 + l;
            int r = slot >> 2, qv = slot & 3;
            const f16* g0 = WH + (size_t)(n0b + r) * EE + k0 + qv * 8;
            const f16* g1 = WL + (size_t)(n0b + r) * EE + k0 + qv * 8;
            dma16(g0, (char*)&W_s[bf][0][0][0] + w * 1024);
            dma16(g1, (char*)&W_s[bf][1][0][0] + w * 1024);
            if (z) {
                const f16* g2 = wvh + (size_t)(n0b + r) * EE + k0 + qv * 8;
                dma16(g2, (char*)&W_s[bf][2][0][0] + w * 1024);
            }
        }
    };

    auto comp = [&](int bf) {
        f16x8 Ahf[4], Alf[4], Bh[2], Bl[2], Bv[2];
#pragma unroll
        for (int mi = 0; mi < 4; ++mi) {
            Ahf[mi] = *(const f16x8*)&A_s[bf][0][wm * 64 + mi * 16 + fr][fc * 8];
            Alf[mi] = *(const f16x8*)&A_s[bf][1][wm * 64 + mi * 16 + fr][fc * 8];
        }
#pragma unroll
        for (int nj = 0; nj < 2; ++nj) {
            Bh[nj] = *(const f16x8*)&W_s[bf][0][wn * 32 + nj * 16 + fr][fc * 8];
            Bl[nj] = *(const f16x8*)&W_s[bf][1][wn * 32 + nj * 16 + fr][fc * 8];
            if (z) Bv[nj] = *(const f16x8*)&W_s[bf][2][wn * 32 + nj * 16 + fr][fc * 8];
        }
        __builtin_amdgcn_s_setprio(1);
#pragma unroll
        for (int mi = 0; mi < 4; ++mi)
#pragma unroll
            for (int nj = 0; nj < 2; ++nj) {
                accK[mi][nj] = __builtin_amdgcn_mfma_f32_16x16x32_f16(
                    Ahf[mi], Bh[nj], accK[mi][nj], 0, 0, 0);
                accK[mi][nj] = __builtin_amdgcn_mfma_f32_16x16x32_f16(
                    Ahf[mi], Bl[nj], accK[mi][nj], 0, 0, 0);
                accK[mi][nj] = __builtin_amdgcn_mfma_f32_16x16x32_f16(
                    Alf[mi], Bh[nj], accK[mi][nj], 0, 0, 0);
                if (z)
                    accV[mi][nj] = __builtin_amdgcn_mfma_f32_16x16x32_f16(
                        Ahf[mi], Bv[nj], accV[mi][nj], 0, 0, 0);
            }
        __builtin_amdgcn_s_setprio(0);
    };

    stageDMA(0, 0);
    __syncthreads();
    int cur = 0;
    for (int ks = 0; ks < 16; ++ks) {
        if (ks < 15) stageDMA(cur ^ 1, (ks + 1) * 32);
        comp(cur);
        __syncthreads();
        cur ^= 1;
    }

    // ---- epilogue (Ep aliases dead A_s) ----
    const int d0  = n0b >> 3;
    const int kfc = d0 >> 5;
    const int lg2 = (d0 >> 3) & 3;
#pragma unroll
    for (int mi = 0; mi < 4; ++mi)
#pragma unroll
        for (int nj = 0; nj < 2; ++nj)
#pragma unroll
            for (int r = 0; r < 4; ++r)
                Ep[wn * 32 + nj * 16 + fr][wm * 64 + mi * 16 + fc * 4 + r] =
                    (f16)accK[mi][nj][r];
    __syncthreads();
#pragma unroll
    for (int i = 0; i < 4; ++i) {
        int task = t * 4 + i;
        int mr = task >> 3, h = task & 7;
        f16x8 v;
#pragma unroll
        for (int d = 0; d < 8; ++d) v[d] = Ep[8 * d + h][mr];
        if (z == 0) {
            *(f16x8*)&qhi[((size_t)h * BT + m0b + mr) * DD + d0] = v;
        } else {
            int mg = m0b + mr;
            int bb = mg >> 10, key = mg & 1023;
            size_t off = ((((((size_t)h * BB + bb) * 16 + (key >> 6)) * 4 +
                            ((key >> 4) & 3)) * 2 + kfc) * 64 +
                          lg2 * 16 + (key & 15)) * 8;
            *(f16x8*)&kthi[off] = v;
        }
    }
    __syncthreads();
#pragma unroll
    for (int mi = 0; mi < 4; ++mi)
#pragma unroll
        for (int nj = 0; nj < 2; ++nj)
#pragma unroll
            for (int r = 0; r < 4; ++r) {
                float x = accK[mi][nj][r];
                f16 hh = (f16)x;
                Ep[wn * 32 + nj * 16 + fr][wm * 64 + mi * 16 + fc * 4 + r] =
                    (f16)(x - (float)hh);
            }
    __syncthreads();
#pragma unroll
    for (int i = 0; i < 4; ++i) {
        int task = t * 4 + i;
        int mr = task >> 3, h = task & 7;
        f16x8 v;
#pragma unroll
        for (int d = 0; d < 8; ++d) v[d] = Ep[8 * d + h][mr];
        if (z == 0) {
            *(f16x8*)&qlo[((size_t)h * BT + m0b + mr) * DD + d0] = v;
        } else {
            int mg = m0b + mr;
            int bb = mg >> 10, key = mg & 1023;
            size_t off = ((((((size_t)h * BB + bb) * 16 + (key >> 6)) * 4 +
                            ((key >> 4) & 3)) * 2 + kfc) * 64 +
                          lg2 * 16 + (key & 15)) * 8;
            *(f16x8*)&ktlo[off] = v;
        }
    }
    if (z) {
        __syncthreads();
#pragma unroll
        for (int mi = 0; mi < 4; ++mi)
#pragma unroll
            for (int nj = 0; nj < 2; ++nj)
#pragma unroll
                for (int r = 0; r < 4; ++r)
                    Ep[wn * 32 + nj * 16 + fr][wm * 64 + mi * 16 + fc * 4 + r] =
                        (f16)accV[mi][nj][r];
        __syncthreads();
        // V fragment-packed store: vP[h][tile][kf][dvt][lane][8]
#pragma unroll
        for (int i = 0; i < 4; ++i) {
            int task = t * 4 + i;
            int mg = task & 15, nn = task >> 4;
            int h = nn & 7, dl = nn >> 3;
            int d = d0 + dl;
            int koff = m0b + mg * 8;
            int tile = koff >> 6;
            int kf   = (koff >> 5) & 1;
            int lgv  = (koff >> 3) & 3;
            int dvt  = d >> 4, lqd = d & 15;
            f16x8 v = *(const f16x8*)&Ep[nn][mg * 8];
            size_t off = (((((size_t)h * 64 + tile) * 2 + kf) * 4 + dvt) * 64 +
                          lgv * 16 + lqd) * 8;
            *(f16x8*)&vP[off] = v;
        }
    }
}

// ---------------------------------------------------------------------------
// Output GEMM: out = ctx(f16) @ Wo (f16) -> fp32. Tile 64x64, BK=64.
// ---------------------------------------------------------------------------
__global__ __launch_bounds__(256) void outmm_k(const f16* __restrict__ Af,
                                               const f16* __restrict__ WThi,
                                               float* __restrict__ out) {
    __shared__ __align__(16) f16 Ah_s[2][64][72];
    __shared__ __align__(16) f16 Wh_s[2][64][72];

    const int t = threadIdx.x;
    const int w = t >> 6, l = t & 63;
    const int wm = w >> 1, wn = w & 1;
    const int fr = l & 15, fc = l >> 4;
    const int m0b = blockIdx.x * 64;
    const int n0b = blockIdx.y * 64;
    const int sr = t >> 2, sch = t & 3;

    f32x4 acc[2][2];
#pragma unroll
    for (int i = 0; i < 2; ++i)
#pragma unroll
        for (int j = 0; j < 2; ++j) acc[i][j] = f32x4{0.f, 0.f, 0.f, 0.f};

    f16x8 af[2], wf[2];
    auto loadAB = [&](int k0) {
#pragma unroll
        for (int i = 0; i < 2; ++i) {
            af[i] = *(const f16x8*)&Af[(size_t)(m0b + sr) * EE + k0 + sch * 16 + i * 8];
            wf[i] = *(const f16x8*)&WThi[(size_t)(n0b + sr) * EE + k0 + sch * 16 + i * 8];
        }
    };
    auto stage = [&](int bf) {
#pragma unroll
        for (int i = 0; i < 2; ++i) {
            *(f16x8*)&Ah_s[bf][sr][sch * 16 + i * 8] = af[i];
            *(f16x8*)&Wh_s[bf][sr][sch * 16 + i * 8] = wf[i];
        }
    };

    loadAB(0);
    stage(0);
    __syncthreads();
    int cur = 0;
    for (int ks = 0; ks < 8; ++ks) {
        if (ks < 7) loadAB((ks + 1) * 64);
        f16x8 Ahf[2][2], Bhf[2][2];
#pragma unroll
        for (int mi = 0; mi < 2; ++mi)
#pragma unroll
            for (int kb = 0; kb < 2; ++kb)
                Ahf[mi][kb] =
                    *(const f16x8*)&Ah_s[cur][wm * 32 + mi * 16 + fr][kb * 32 + fc * 8];
#pragma unroll
        for (int nj = 0; nj < 2; ++nj)
#pragma unroll
            for (int kb = 0; kb < 2; ++kb)
                Bhf[nj][kb] =
                    *(const f16x8*)&Wh_s[cur][wn * 32 + nj * 16 + fr][kb * 32 + fc * 8];
        __builtin_amdgcn_s_setprio(1);
#pragma unroll
        for (int mi = 0; mi < 2; ++mi)
#pragma unroll
            for (int nj = 0; nj < 2; ++nj)
#pragma unroll
                for (int kb = 0; kb < 2; ++kb)
                    acc[mi][nj] = __builtin_amdgcn_mfma_f32_16x16x32_f16(
                        Ahf[mi][kb], Bhf[nj][kb], acc[mi][nj], 0, 0, 0);
        __builtin_amdgcn_s_setprio(0);
        if (ks < 7) stage(cur ^ 1);
        __syncthreads();
        cur ^= 1;
    }

#pragma unroll
    for (int mi = 0; mi < 2; ++mi)
#pragma unroll
        for (int nj = 0; nj < 2; ++nj)
#pragma unroll
            for (int r = 0; r < 4; ++r)
                out[(size_t)(m0b + wm * 32 + mi * 16 + fc * 4 + r) * EE +
                    n0b + wn * 32 + nj * 16 + fr] = acc[mi][nj][r];
}

// ---------------------------------------------------------------------------
// Block-shared LDS flash attention, 32x32x16 MFMA: each wave owns 32 q-rows,
// halving LDS operand bytes per FLOP vs 16x16. Block = 4 waves = 128 q-rows.
// Grid 256 (h on bid&7 -> XCD-local). K hi/lo + V tiles DMA-staged in LDS.
// Swapped QK^T: lane holds 32 scores for q = lane&31; softmax per-lane +
// one shfl_xor(32). P via per-wave [32][72] LDS buffer.
// ---------------------------------------------------------------------------
__global__ __launch_bounds__(256) void attn_mfma_k(const f16* __restrict__ qhiP,
    const f16* __restrict__ qloP, const f16* __restrict__ kthiP,
    const f16* __restrict__ ktloP, const f16* __restrict__ vP,
    f16* __restrict__ ctx) {
    __shared__ __align__(16) f16 KhiL[2][4096];    // 8 KB per buffer
    __shared__ __align__(16) f16 KloL[2][4096];
    __shared__ __align__(16) f16 VL[2][4096];
    __shared__ __align__(16) f16 Pl[4][32][72];    // per-wave P[q][key]

    const int bid = blockIdx.x;          // 0..255
    const int bx = (bid >> 3) & 7;       // q-block 0..7
    const int h  = bid & 7;              // same h -> same XCD
    const int b  = bid >> 6;

    const int t  = threadIdx.x;          // 0..255
    const int w  = t >> 6;
    const int l  = t & 63;
    const int lh = l >> 5;               // half 0/1
    const int lq = l & 31;               // q within wave-tile / col index
    const int l16 = l & 15;
    const int q0 = bx * 128 + w * 32;
    const size_t plane = ((size_t)h * BT + (size_t)b * TT) * DD;

    // Q fragments (B-operand 32x32): lane -> q=lq, d = dw*16 + lh*8 + e
    f16x8 Qhi[4], Qlo[4];
#pragma unroll
    for (int dw = 0; dw < 4; ++dw) {
        size_t qo = plane + (size_t)(q0 + lq) * DD + dw * 16 + lh * 8;
        Qhi[dw] = *(const f16x8*)&qhiP[qo];
        Qlo[dw] = *(const f16x8*)&qloP[qo];
    }

    f32x16 Oacc[2];
#pragma unroll
    for (int i = 0; i < 2; ++i)
#pragma unroll
        for (int r = 0; r < 16; ++r) Oacc[i][r] = 0.f;
    float m = -1e30f, lsum = 0.f;

    const f16* khb = kthiP + (((size_t)h * BB + b) << 16);
    const f16* klb = ktloP + (((size_t)h * BB + b) << 16);
    const f16* vtb = vP + ((size_t)h * 64 + b * 16) * 4096;

    auto stageDMA = [&](int bf, int tile) {
#pragma unroll
        for (int i = 0; i < 2; ++i) {
            const f16* ks = khb + (size_t)tile * 4096 + (i * 256 + t) * 8;
            const f16* ls = klb + (size_t)tile * 4096 + (i * 256 + t) * 8;
            const f16* vs = vtb + (size_t)tile * 4096 + (i * 256 + t) * 8;
            dma16(ks, (char*)&KhiL[bf][0] + (i * 4 + w) * 1024);
            dma16(ls, (char*)&KloL[bf][0] + (i * 4 + w) * 1024);
            dma16(vs, (char*)&VL[bf][0] + (i * 4 + w) * 1024);
        }
    };

    // QK^T for one 32-key block kb: S^T[key][q], 3-product split fp16
    auto QK32 = [&](int bf, int kb) -> f32x16 {
        f32x16 c;
#pragma unroll
        for (int r = 0; r < 16; ++r) c[r] = 0.f;
        const int kt = kb * 2 + (lq >> 4);   // key16-block
        __builtin_amdgcn_s_setprio(1);
#pragma unroll
        for (int dw = 0; dw < 4; ++dw) {
            int kf = dw >> 1, lg = (dw & 1) * 2 + lh;
            int off = ((kt * 2 + kf) * 64 + lg * 16 + l16) * 8;
            f16x8 shi = *(const f16x8*)&KhiL[bf][off];
            f16x8 slo = *(const f16x8*)&KloL[bf][off];
            c = __builtin_amdgcn_mfma_f32_32x32x16_f16(shi, Qhi[dw], c, 0, 0, 0);
            c = __builtin_amdgcn_mfma_f32_32x32x16_f16(shi, Qlo[dw], c, 0, 0, 0);
            c = __builtin_amdgcn_mfma_f32_32x32x16_f16(slo, Qhi[dw], c, 0, 0, 0);
        }
        __builtin_amdgcn_s_setprio(0);
        return c;
    };

    auto SMPV = [&](int bf, const f32x16& S0, const f32x16& S1) {
        float sv[32];
#pragma unroll
        for (int r = 0; r < 16; ++r) { sv[r] = S0[r]; sv[16 + r] = S1[r]; }
        // tree max
        float mx[16];
#pragma unroll
        for (int i = 0; i < 16; ++i) mx[i] = fmaxf(sv[i], sv[i + 16]);
#pragma unroll
        for (int st = 8; st > 0; st >>= 1)
#pragma unroll
            for (int i = 0; i < st; ++i) mx[i] = fmaxf(mx[i], mx[i + st]);
        float tm = fmaxf(mx[0], __shfl_xor(mx[0], 32));

        bool skip = __all(tm <= m + 8.0f);
        float Mn = m, corr = 1.0f;
        if (!skip) {
            Mn = fmaxf(m, tm);
            corr = __expf(m - Mn);
        }
        f16 ph[32];
        float sm[16];
#pragma unroll
        for (int i = 0; i < 16; ++i) {
            float p0 = __expf(sv[i] - Mn);
            float p1 = __expf(sv[i + 16] - Mn);
            ph[i] = (f16)p0; ph[i + 16] = (f16)p1;
            sm[i] = p0 + p1;
        }
#pragma unroll
        for (int st = 8; st > 0; st >>= 1)
#pragma unroll
            for (int i = 0; i < st; ++i) sm[i] += sm[i + st];
        float ps = sm[0] + __shfl_xor(sm[0], 32);
        if (skip) {
            lsum += ps;
        } else {
            lsum = lsum * corr + ps;
            m = Mn;
        }

        // write P[q=lq][key]: rows (j + 8*rg + 4*lh) + kb*32, packed pairs
#pragma unroll
        for (int kb = 0; kb < 2; ++kb)
#pragma unroll
            for (int rg = 0; rg < 4; ++rg) {
                int col = kb * 32 + 8 * rg + 4 * lh;
                int i0 = kb * 16 + rg * 4;
                union { f16 h2[2]; unsigned int u; } pk0, pk1;
                pk0.h2[0] = ph[i0];     pk0.h2[1] = ph[i0 + 1];
                pk1.h2[0] = ph[i0 + 2]; pk1.h2[1] = ph[i0 + 3];
                *(unsigned int*)&Pl[w][lq][col]     = pk0.u;
                *(unsigned int*)&Pl[w][lq][col + 2] = pk1.u;
            }

        if (!skip) {
            float cq[16];
#pragma unroll
            for (int r = 0; r < 16; ++r) {
                int rowq = (r & 3) + 8 * (r >> 2) + 4 * lh;
                cq[r] = __shfl(corr, rowq);
            }
#pragma unroll
            for (int db = 0; db < 2; ++db)
#pragma unroll
                for (int r = 0; r < 16; ++r) Oacc[db][r] *= cq[r];
        }

        // PV: O[q][d] += P @ V
        __builtin_amdgcn_s_setprio(1);
#pragma unroll
        for (int kw = 0; kw < 4; ++kw) {
            f16x8 pa = *(const f16x8*)&Pl[w][lq][kw * 16 + lh * 8];
            int kf = kw >> 1, lgv = (kw & 1) * 2 + lh;
#pragma unroll
            for (int db = 0; db < 2; ++db) {
                int dvt = db * 2 + (lq >> 4);
                f16x8 bv = *(const f16x8*)&VL[bf][((kf * 4 + dvt) * 64 +
                                                   lgv * 16 + l16) * 8];
                Oacc[db] = __builtin_amdgcn_mfma_f32_32x32x16_f16(
                    pa, bv, Oacc[db], 0, 0, 0);
            }
        }
        __builtin_amdgcn_s_setprio(0);
    };

    stageDMA(0, 0);
    __syncthreads();
    int cur = 0;
    for (int tile = 0; tile < 16; ++tile) {
        if (tile + 1 < 16) stageDMA(cur ^ 1, tile + 1);   // DMA a tile ahead
        f32x16 S0 = QK32(cur, 0);
        f32x16 S1 = QK32(cur, 1);
        SMPV(cur, S0, S1);
        __syncthreads();
        cur ^= 1;
    }

    float linv = 1.0f / lsum;
#pragma unroll
    for (int r = 0; r < 16; ++r) {
        int rowq = (r & 3) + 8 * (r >> 2) + 4 * lh;
        float lv = __shfl(linv, rowq);
        f16* crow = ctx + (size_t)(b * TT + q0 + rowq) * EE + h * DD;
        crow[lq]      = (f16)(Oacc[0][r] * lv);
        crow[32 + lq] = (f16)(Oacc[1][r] * lv);
    }
}

// ---------------------------------------------------------------------------
extern "C" void kernel_launch(void* const* d_in, const int* in_sizes, int n_in,
                              void* d_out, int out_size, void* d_ws, size_t ws_size,
                              hipStream_t stream) {
    const float* q  = (const float*)d_in[0];
    const float* kv = (const float*)d_in[1];
    const float* Wq = (const float*)d_in[2];
    const float* Wk = (const float*)d_in[3];
    const float* Wv = (const float*)d_in[4];
    const float* Wo = (const float*)d_in[5];
    float* out = (float*)d_out;

    f16* ws = (f16*)d_ws;
    const size_t PL  = (size_t)HH * BT * DD;   // 2,097,152 f16 per plane
    const size_t WPL = (size_t)EE * EE;
    f16* qhi   = ws + 0 * PL;
    f16* qlo   = ws + 1 * PL;
    f16* kthi  = ws + 2 * PL;      // packed K frags [H][B][16][4][2][64][8]
    f16* ktlo  = ws + 3 * PL;
    f16* vPck  = ws + 4 * PL;      // packed V frags [H][64][2][4][64][8]
    f16* ctx   = ws + 5 * PL;      // [BT][512]
    f16* qAhi  = ws + 6 * PL;
    f16* qAlo  = ws + 7 * PL;
    f16* kvAhi = ws + 8 * PL;
    f16* kvAlo = ws + 9 * PL;
    f16* wqh = ws + 10 * PL;
    f16* wql = wqh + 1 * WPL;
    f16* wkh = wqh + 2 * WPL;
    f16* wkl = wqh + 3 * WPL;
    f16* wvh = wqh + 4 * WPL;
    f16* woh = wqh + 5 * WPL;

    prep_k<<<dim3(1024, 6), dim3(256), 0, stream>>>(
        q, kv, Wq, Wk, Wv, Wo, wqh, wql, wkh, wkl, wvh, woh,
        qAhi, qAlo, kvAhi, kvAlo);

    proj_k<<<dim3(BT / 128, EE / 64, 2), dim3(256), 0, stream>>>(
        qAhi, qAlo, kvAhi, kvAlo, wqh, wql, wkh, wkl, wvh,
        qhi, qlo, kthi, ktlo, vPck);

    attn_mfma_k<<<dim3(256), dim3(256), 0, stream>>>(
        qhi, qlo, kthi, ktlo, vPck, ctx);

    outmm_k<<<dim3(BT / 64, EE / 64), dim3(256), 0, stream>>>(ctx, woh, out);
}